// Round 10
// baseline (101.932 us; speedup 1.0000x reference)
//
#include <hip/hip_runtime.h>

typedef unsigned short u16;
typedef unsigned int u32;
typedef __attribute__((ext_vector_type(8))) short short8;
typedef __attribute__((ext_vector_type(4))) float f32x4;

constexpr int kN = 16, kDH = 64, kD = 1024;
constexpr float kEps = 1e-5f;
constexpr float kExp2Scale = 0.18033688011112042f;   // 0.125 * log2(e)

__device__ __forceinline__ u16 f2b(float f) {
  u32 u = __float_as_uint(f);
  u += 0x7fffu + ((u >> 16) & 1u);   // round-to-nearest-even bf16
  return (u16)(u >> 16);
}
__device__ __forceinline__ float b2f(u32 bits) {
  return __uint_as_float(bits << 16);
}

// 16B direct global->LDS DMA. LDS dest is wave-uniform base + lane*16 (HW rule).
__device__ __forceinline__ void gload16(const u16* g, u16* l) {
  __builtin_amdgcn_global_load_lds(
      (const __attribute__((address_space(1))) void*)g,
      (__attribute__((address_space(3))) void*)l, 16, 0, 0);
}

// Swizzled read of a short8 frag from a [rows][64el] LDS tile whose SOURCE was
// pre-swizzled chunk-wise: el ^= ((row&7)<<3). colel must be a multiple of 8.
__device__ __forceinline__ short8 read8sw(const u16* base, int row, int colel) {
  return *(const short8*)(base + (row << 6) + (colel ^ ((row & 7) << 3)));
}

// k-permutation baked into v^T / U^T layouts so the in-register P (S^T C/D
// layout: lane lk holds k = t*16 + lk*4 + r) is directly a valid MFMA A-frag.
__device__ __forceinline__ int permS(int s) {
  return (s & ~31) + ((s & 12) << 1) + ((s & 16) >> 2) + (s & 3);
}

// ---------------- fused fp32 -> bf16 cast for all 4 tensors ----------------
__global__ __launch_bounds__(256) void cvt_all(const float* __restrict__ h,
                                               const float* __restrict__ wq,
                                               const float* __restrict__ wkv,
                                               const float* __restrict__ wo,
                                               u16* __restrict__ hb, u16* __restrict__ wqb,
                                               u16* __restrict__ wkvb, u16* __restrict__ wob) {
  long idx = (long)blockIdx.x * 256 + threadIdx.x;  // 4-element group index
  const float* in;
  u16* out;
  long base;
  if (idx < 524288L) { in = h; out = hb; base = idx; }
  else if (idx < 786432L) { in = wq; out = wqb; base = idx - 524288L; }
  else if (idx < 1310720L) { in = wkv; out = wkvb; base = idx - 786432L; }
  else { in = wo; out = wob; base = idx - 1310720L; }
  float4 v = *(const float4*)(in + base * 4);
  uint2 o;
  o.x = (u32)f2b(v.x) | ((u32)f2b(v.y) << 16);
  o.y = (u32)f2b(v.z) | ((u32)f2b(v.w) << 16);
  *(uint2*)(out + base * 4) = o;
}

// ---------------- tiled NT GEMM (projections), BK=64, T2-swizzled LDS ----------------
struct GemmParams {
  const u16* A; long ldA;
  const u16* B; long ldB;
  const u16* B2;               // MODE6: Wkv
  int K;
  u16* ob; float* of; long ldO;
  u16* ob2;                    // MODE6: k out
  u16* aux_b16;                // MODE6: vtb (v transposed, k-permuted)
};

// MODE: 5=fp32 plain, 6=fused qkv (q / k / v-transposed-permuted by col range)
// BM x BN tile, BK=64, double-buffered LDS; 4 waves arranged (BM/(MF*16)) x (BN/(NF*16));
// wave computes (MF*16) x (NF*16) via 2*MF*NF mfma_f32_16x16x32_bf16 per K-step.
// LDS tiles are [row][64el] with chunk-level XOR swizzle (source pre-swizzled,
// linear LDS dest per global_load_lds HW rule, reads via read8sw).
template <int MODE, int BM, int BN, int MF, int NF>
__global__ __launch_bounds__(256) void gemm_tile(GemmParams p) {
  __shared__ __align__(16) u16 sm[2][(BM + BN) * 64];
  constexpr int WN = BN / (NF * 16);            // waves along N
  constexpr int NLD = (BM + BN) / 32;           // 16B chunks per thread per K-step
  const int tid = threadIdx.x, lane = tid & 63, w = tid >> 6;
  const int wR = w / WN, wC = w % WN;
  const int lr = lane & 15, lk = lane >> 4;
  const int bm0 = blockIdx.y * BM, bn0 = blockIdx.x * BN;
  const int m0 = bm0 + wR * (MF * 16), n0 = bn0 + wC * (NF * 16);
  const u16* A = p.A;
  const u16* B = (MODE == 6 && bn0 >= 1024) ? (p.B2 - 1048576) : p.B;

  f32x4 acc[MF][NF] = {};

  auto stage = [&](int k0, int buf) {
#pragma unroll
    for (int i = 0; i < NLD; ++i) {
      const int cbase = i * 256 + w * 64;   // wave-uniform; A/B boundary at BM*8 (mult of 256)
      const int c = cbase + lane;
      const int row = c >> 3;                       // tile row (A: 0..BM-1, B: BM..)
      const int col = ((c & 7) ^ (row & 7)) * 8;    // pre-swizzled source column
      const u16* g;
      if (row < BM) {
        g = A + (long)(bm0 + row) * p.ldA + k0 + col;
      } else {
        g = B + (long)(bn0 + (row - BM)) * p.ldB + k0 + col;
      }
      gload16(g, &sm[buf][(size_t)c * 8]);
    }
  };

  auto compute = [&](int buf) {
    const u16* As = sm[buf];
    const u16* Bs = sm[buf] + BM * 64;
    short8 af[MF][2], bf[NF][2];
#pragma unroll
    for (int mi = 0; mi < MF; ++mi)
#pragma unroll
      for (int kk = 0; kk < 2; ++kk)
        af[mi][kk] = read8sw(As, (wR * MF + mi) * 16 + lr, kk * 32 + lk * 8);
#pragma unroll
    for (int ni = 0; ni < NF; ++ni)
#pragma unroll
      for (int kk = 0; kk < 2; ++kk)
        bf[ni][kk] = read8sw(Bs, (wC * NF + ni) * 16 + lr, kk * 32 + lk * 8);
#pragma unroll
    for (int kk = 0; kk < 2; ++kk)
#pragma unroll
      for (int mi = 0; mi < MF; ++mi)
#pragma unroll
        for (int ni = 0; ni < NF; ++ni)
          acc[mi][ni] = __builtin_amdgcn_mfma_f32_16x16x32_bf16(af[mi][kk], bf[ni][kk], acc[mi][ni], 0, 0, 0);
  };

  const int nt = p.K / 64;
  stage(0, 0);
  __syncthreads();
  for (int t = 0; t < nt - 1; ++t) {
    stage((t + 1) * 64, (t & 1) ^ 1);
    compute(t & 1);
    __syncthreads();
  }
  compute((nt - 1) & 1);

#pragma unroll
  for (int mi = 0; mi < MF; ++mi)
#pragma unroll
    for (int ni = 0; ni < NF; ++ni)
#pragma unroll
      for (int r = 0; r < 4; ++r) {
        int row = m0 + mi * 16 + lk * 4 + r;   // C/D: row=(lane>>4)*4+reg
        int col = n0 + ni * 16 + lr;           //      col=lane&15
        float v = acc[mi][ni][r];
        if constexpr (MODE == 6) {
          if (col < 1024) {
            p.ob[(long)row * 1024 + col] = f2b(v);
          } else if (col < 2048) {
            p.ob2[(long)row * 1024 + (col - 1024)] = f2b(v);
          } else {
            int c = col - 2048, n = c >> 6, dd = c & 63, s = row >> 1, b = row & 1;
            p.aux_b16[(((long)((b * kN + n) * kDH + dd)) << 10) + permS(s)] = f2b(v);
          }
        } else {
          p.of[(long)row * p.ldO + col] = v;
        }
      }
}

// ---------------- fused twicing attention (flash, 1 barrier/K-tile) ----------------
// Per (z, q-block of 64): wave w owns q-rows q0=w*16..+16. Per K-tile j (64 keys):
//   S^T via mfma(K, Qfrag) -> lane holds P[q=lr][k=kt*16+lk*4+r] ;
//   exp2(s*c) -> pack bf16 in REGISTERS -> directly the PV A-frag (B operand layouts
//   are k-permuted via permS at write time) ; acc += P * Btile. One barrier per j.
// PASS1 (bp=v^T): writes normalized U^T (permuted) + linv. PASS2 (bp=U^T):
// vec = 2*U - (P@U)*linv.
template <bool PASS1>
__global__ __launch_bounds__(256, 4) void flash_tw(const u16* __restrict__ qp,
                                                   const u16* __restrict__ kp,
                                                   const u16* __restrict__ bp,
                                                   float* __restrict__ linv_g,
                                                   u16* __restrict__ outp) {
  __shared__ __align__(16) u16 Ks[2][64 * 64];   // 16 KB
  __shared__ __align__(16) u16 Bs[2][64 * 64];   // 16 KB
  __shared__ float lred[64], lrinv[64];
  const int z = blockIdx.y, qb0 = blockIdx.x * 64;
  const int tid = threadIdx.x, lane = tid & 63, w = tid >> 6;
  const int lr = lane & 15, lk = lane >> 4;
  const int q0 = w * 16;

  auto stageKB = [&](int j, int buf) {
#pragma unroll
    for (int i = 0; i < 2; ++i) {
      int c = i * 256 + w * 64 + lane;
      int row = c >> 3, col = (c & 7) ^ (row & 7);
      gload16(kp + (long)(j * 64 + row) * 2048 + z * 64 + col * 8, Ks[buf] + c * 8);
      gload16(bp + (long)z * 65536 + (long)row * 1024 + j * 64 + col * 8, Bs[buf] + c * 8);
    }
  };

  // Q fragments straight from global, once (S-phase B operand): Q[q0+lr][dh]
  short8 qf[2];
#pragma unroll
  for (int kk = 0; kk < 2; ++kk)
    qf[kk] = *(const short8*)(qp + (long)(qb0 + q0 + lr) * 2048 + z * 64 + kk * 32 + lk * 8);

  stageKB(0, 0);
  __syncthreads();

  f32x4 acc[4] = {};
  float lsum = 0.f;

  for (int j = 0; j < 16; ++j) {
    const int cur = j & 1;
    if (j < 15) stageKB(j + 1, cur ^ 1);
    // S^T phase: st[kt] covers k = kt*16.., q = q0.. (this wave's rows)
    f32x4 st[4];
#pragma unroll
    for (int kt = 0; kt < 4; ++kt) st[kt] = (f32x4){0.f, 0.f, 0.f, 0.f};
#pragma unroll
    for (int kk = 0; kk < 2; ++kk)
#pragma unroll
      for (int kt = 0; kt < 4; ++kt) {
        short8 kf = read8sw(Ks[cur], kt * 16 + lr, kk * 32 + lk * 8);
        st[kt] = __builtin_amdgcn_mfma_f32_16x16x32_bf16(kf, qf[kk], st[kt], 0, 0, 0);
      }
    // exp2(score * 0.125*log2e) -> bf16 pack (lane: q=lr, k=kt*16+lk*4+{0..3})
    uint2 pk[4];
#pragma unroll
    for (int kt = 0; kt < 4; ++kt) {
      float e0 = exp2f(st[kt][0] * kExp2Scale);
      float e1 = exp2f(st[kt][1] * kExp2Scale);
      float e2 = exp2f(st[kt][2] * kExp2Scale);
      float e3 = exp2f(st[kt][3] * kExp2Scale);
      if (PASS1) lsum += e0 + e1 + e2 + e3;
      pk[kt].x = (u32)f2b(e0) | ((u32)f2b(e1) << 16);
      pk[kt].y = (u32)f2b(e2) | ((u32)f2b(e3) << 16);
    }
    // U phase: acc[dt] += P * Btile ; P-frag = pk pair (permuted-k A-frag)
#pragma unroll
    for (int kk = 0; kk < 2; ++kk) {
      union { u32 u[4]; short8 s8; } pa;
      pa.u[0] = pk[kk * 2].x; pa.u[1] = pk[kk * 2].y;
      pa.u[2] = pk[kk * 2 + 1].x; pa.u[3] = pk[kk * 2 + 1].y;
#pragma unroll
      for (int dt = 0; dt < 4; ++dt) {
        short8 bf = read8sw(Bs[cur], dt * 16 + lr, kk * 32 + lk * 8);
        acc[dt] = __builtin_amdgcn_mfma_f32_16x16x32_bf16(pa.s8, bf, acc[dt], 0, 0, 0);
      }
    }
    __syncthreads();   // drains staging vmcnt; guards buffer reuse
  }

  float iv[4];
  if (PASS1) {
    lsum += __shfl_xor(lsum, 16);
    lsum += __shfl_xor(lsum, 32);
    if (lane < 16) lred[q0 + lr] = lsum;
    __syncthreads();
    if (tid < 64) {
      float v = 1.f / lred[tid];
      lrinv[tid] = v;
      linv_g[(long)z * 1024 + qb0 + tid] = v;
    }
    __syncthreads();
#pragma unroll
    for (int r = 0; r < 4; ++r) iv[r] = lrinv[q0 + lk * 4 + r];
  } else {
    float4 l4 = *(const float4*)(linv_g + (long)z * 1024 + qb0 + q0 + lk * 4);
    iv[0] = l4.x; iv[1] = l4.y; iv[2] = l4.z; iv[3] = l4.w;
  }

  const int sq = qb0 + q0 + lk * 4;            // true q of acc rows (aligned 4)
  const int sp = (sq & ~31) + ((sq & 12) << 1) + ((sq & 16) >> 2);  // permuted base
#pragma unroll
  for (int dt = 0; dt < 4; ++dt) {
    const int d = dt * 16 + lr;                // C/D col
    if (PASS1) {
      uint2 o_;
      o_.x = (u32)f2b(acc[dt][0] * iv[0]) | ((u32)f2b(acc[dt][1] * iv[1]) << 16);
      o_.y = (u32)f2b(acc[dt][2] * iv[2]) | ((u32)f2b(acc[dt][3] * iv[3]) << 16);
      *(uint2*)(outp + (long)z * 65536 + (long)d * 1024 + sp) = o_;
    } else {
      uint2 ut = *(const uint2*)(bp + (long)z * 65536 + (long)d * 1024 + sp);
      float u0 = b2f(ut.x & 0xffffu), u1 = b2f(ut.x >> 16);
      float u2 = b2f(ut.y & 0xffffu), u3 = b2f(ut.y >> 16);
      long ob = (long)sq * 2048 + z * 64 + d;
      outp[ob]        = f2b(2.f * u0 - acc[dt][0] * iv[0]);
      outp[ob + 2048] = f2b(2.f * u1 - acc[dt][1] * iv[1]);
      outp[ob + 4096] = f2b(2.f * u2 - acc[dt][2] * iv[2]);
      outp[ob + 6144] = f2b(2.f * u3 - acc[dt][3] * iv[3]);
    }
  }
}

// ---------------- residual + LayerNorm ----------------
__global__ __launch_bounds__(256) void resid_ln(const float* __restrict__ h,
                                                const float* __restrict__ attn,
                                                const float* __restrict__ gamma,
                                                const float* __restrict__ beta,
                                                float* __restrict__ out) {
  __shared__ float rs[4], rs2[4];
  const long row = blockIdx.x;
  const int t = threadIdx.x;
  long base = (row << 10) + t * 4;
  float4 hv = *(const float4*)(h + base);
  float4 av = *(const float4*)(attn + base);
  float x0 = hv.x + av.x, x1 = hv.y + av.y, x2 = hv.z + av.z, x3 = hv.w + av.w;
  float s = x0 + x1 + x2 + x3;
  float s2 = x0 * x0 + x1 * x1 + x2 * x2 + x3 * x3;
  for (int o = 32; o; o >>= 1) { s += __shfl_xor(s, o); s2 += __shfl_xor(s2, o); }
  int wid = t >> 6;
  if ((t & 63) == 0) { rs[wid] = s; rs2[wid] = s2; }
  __syncthreads();
  s = rs[0] + rs[1] + rs[2] + rs[3];
  s2 = rs2[0] + rs2[1] + rs2[2] + rs2[3];
  float mean = s * (1.f / 1024.f);
  float var = s2 * (1.f / 1024.f) - mean * mean;
  float rstd = rsqrtf(var + kEps);
  int d = t * 4;
  float4 g = *(const float4*)(gamma + d);
  float4 bt = *(const float4*)(beta + d);
  float4 o_;
  o_.x = (x0 - mean) * rstd * g.x + bt.x;
  o_.y = (x1 - mean) * rstd * g.y + bt.y;
  o_.z = (x2 - mean) * rstd * g.z + bt.z;
  o_.w = (x3 - mean) * rstd * g.w + bt.w;
  *(float4*)(out + base) = o_;
}

extern "C" void kernel_launch(void* const* d_in, const int* in_sizes, int n_in,
                              void* d_out, int out_size, void* d_ws, size_t ws_size,
                              hipStream_t stream) {
  const float* h = (const float*)d_in[0];
  const float* Wq = (const float*)d_in[1];
  const float* Wkv = (const float*)d_in[2];
  const float* Wo = (const float*)d_in[3];
  const float* gamma = (const float*)d_in[4];
  const float* beta = (const float*)d_in[5];
  float* out = (float*)d_out;

  char* ws = (char*)d_ws;
  size_t off = 0;
  auto alloc = [&](size_t bytes) -> void* {
    void* p = ws + off;
    off = (off + bytes + 255) & ~(size_t)255;
    return p;
  };
  u16* hb = (u16*)alloc(2097152ULL * 2);
  u16* Wqb = (u16*)alloc(1048576ULL * 2);
  u16* Wkvb = (u16*)alloc(2097152ULL * 2);
  u16* Wob = (u16*)alloc(1048576ULL * 2);
  u16* qb = (u16*)alloc(2097152ULL * 2);      // [S, B*N*DH]
  u16* kb = (u16*)alloc(2097152ULL * 2);      // [S, B*N*DH]
  u16* vtb = (u16*)alloc(2097152ULL * 2);     // [B,N,DH,S-perm]
  u16* Ut = (u16*)alloc(2097152ULL * 2);      // [B,N,DH,S-perm] (normalized U^T)
  float* linv = (float*)alloc(32768ULL * 4);  // [B,N,S]
  u16* vecb = (u16*)alloc(2097152ULL * 2);    // [S, B*N*DH]
  float* attn = (float*)alloc(2097152ULL * 4);// [S,B,D]
  (void)ws_size; (void)n_in; (void)in_sizes; (void)out_size;

  // fused casts (h, Wq, Wkv, Wo)
  cvt_all<<<6144, 256, 0, stream>>>(h, Wq, Wkv, Wo, hb, Wqb, Wkvb, Wob);

  // fused qkv: [q | k | v^T-perm] = h @ [Wq;Wkv]^T  (M=2048, N=3072, K=1024)
  // 128x64 tile: 4 waves stacked in M, 16 MFMA/wave/K-step, 768 blocks (3 full CU-rounds)
  {
    GemmParams p{};
    p.A = hb; p.ldA = 1024;
    p.B = Wqb; p.ldB = 1024; p.B2 = Wkvb;
    p.K = 1024; p.ob = qb; p.ob2 = kb; p.aux_b16 = vtb;
    gemm_tile<6, 128, 64, 2, 4><<<dim3(48, 16, 1), 256, 0, stream>>>(p);
  }
  // flash pass 1: U = softmax(qk/8) @ V -> Ut (normalized, permuted) + linv
  flash_tw<true><<<dim3(16, 32), 256, 0, stream>>>(qb, kb, vtb, linv, Ut);
  // flash pass 2: vec = 2U - (P @ U) * linv -> vecb
  flash_tw<false><<<dim3(16, 32), 256, 0, stream>>>(qb, kb, Ut, linv, vecb);
  // attn = vec @ Wo^T  (M=2048, N=1024, K=1024), fp32 out; 64x64 tile (512 blocks)
  {
    GemmParams p{};
    p.A = vecb; p.ldA = 1024;
    p.B = Wob; p.ldB = 1024;
    p.K = 1024; p.of = attn; p.ldO = 1024;
    gemm_tile<5, 64, 64, 2, 2><<<dim3(16, 32, 1), 256, 0, stream>>>(p);
  }
  // out = LN(h + attn) * gamma + beta
  resid_ln<<<2048, 256, 0, stream>>>(h, attn, gamma, beta, out);
}

// Round 11
// 94.849 us; speedup vs baseline: 1.0747x; 1.0747x over previous
//
#include <hip/hip_runtime.h>

typedef unsigned short u16;
typedef unsigned int u32;
typedef __attribute__((ext_vector_type(8))) short short8;
typedef __attribute__((ext_vector_type(4))) float f32x4;

constexpr int kN = 16, kDH = 64, kD = 1024;
constexpr float kEps = 1e-5f;
constexpr float kExp2Scale = 0.18033688011112042f;   // 0.125 * log2(e)

__device__ __forceinline__ u16 f2b(float f) {
  u32 u = __float_as_uint(f);
  u += 0x7fffu + ((u >> 16) & 1u);   // round-to-nearest-even bf16
  return (u16)(u >> 16);
}
__device__ __forceinline__ float b2f(u32 bits) {
  return __uint_as_float(bits << 16);
}

// 16B direct global->LDS DMA. LDS dest is wave-uniform base + lane*16 (HW rule).
__device__ __forceinline__ void gload16(const u16* g, u16* l) {
  __builtin_amdgcn_global_load_lds(
      (const __attribute__((address_space(1))) void*)g,
      (__attribute__((address_space(3))) void*)l, 16, 0, 0);
}

// Counted-vmcnt waits (T4): keep prefetch loads in flight across barriers.
__device__ __forceinline__ void wait_vm4() {
  asm volatile("s_waitcnt vmcnt(4)" ::: "memory");
  __builtin_amdgcn_sched_barrier(0);
}
__device__ __forceinline__ void wait_vm0() {
  asm volatile("s_waitcnt vmcnt(0)" ::: "memory");
  __builtin_amdgcn_sched_barrier(0);
}
__device__ __forceinline__ void wait_lgkm0() {
  asm volatile("s_waitcnt lgkmcnt(0)" ::: "memory");
  __builtin_amdgcn_sched_barrier(0);
}

// Swizzled read of a short8 frag from a [rows][64el] LDS tile whose SOURCE was
// pre-swizzled chunk-wise: el ^= ((row&7)<<3). colel must be a multiple of 8.
__device__ __forceinline__ short8 read8sw(const u16* base, int row, int colel) {
  return *(const short8*)(base + (row << 6) + (colel ^ ((row & 7) << 3)));
}

// k-permutation baked into v^T / U^T layouts so the in-register P (S^T C/D
// layout: lane lk holds k = t*16 + lk*4 + r) is directly a valid MFMA A-frag.
__device__ __forceinline__ int permS(int s) {
  return (s & ~31) + ((s & 12) << 1) + ((s & 16) >> 2) + (s & 3);
}

// ---------------- fused fp32 -> bf16 cast for all 4 tensors ----------------
__global__ __launch_bounds__(256) void cvt_all(const float* __restrict__ h,
                                               const float* __restrict__ wq,
                                               const float* __restrict__ wkv,
                                               const float* __restrict__ wo,
                                               u16* __restrict__ hb, u16* __restrict__ wqb,
                                               u16* __restrict__ wkvb, u16* __restrict__ wob) {
  long idx = (long)blockIdx.x * 256 + threadIdx.x;  // 4-element group index
  const float* in;
  u16* out;
  long base;
  if (idx < 524288L) { in = h; out = hb; base = idx; }
  else if (idx < 786432L) { in = wq; out = wqb; base = idx - 524288L; }
  else if (idx < 1310720L) { in = wkv; out = wkvb; base = idx - 786432L; }
  else { in = wo; out = wob; base = idx - 1310720L; }
  float4 v = *(const float4*)(in + base * 4);
  uint2 o;
  o.x = (u32)f2b(v.x) | ((u32)f2b(v.y) << 16);
  o.y = (u32)f2b(v.z) | ((u32)f2b(v.w) << 16);
  *(uint2*)(out + base * 4) = o;
}

// ---------------- tiled NT GEMM (projections), BK=64, T2-swizzled, T4-counted ----------------
struct GemmParams {
  const u16* A; long ldA;
  const u16* B; long ldB;
  const u16* B2;               // MODE6: Wkv
  int K;
  u16* ob; float* of; long ldO;
  u16* ob2;                    // MODE6: k out
  u16* aux_b16;                // MODE6: vtb (v transposed, k-permuted)
};

// MODE: 5=fp32 plain, 6=fused qkv (q / k / v-transposed-permuted by col range)
// 64x64 tile, BK=64, double-buffered (32 KB LDS), 4 waves 2x2, 8 MFMA/wave/K-step.
// Counted-vmcnt pipeline: tile j+1 loads stay in flight across tile-j compute.
template <int MODE>
__global__ __launch_bounds__(256) void gemm_tile(GemmParams p) {
  __shared__ __align__(16) u16 sm[2][8192];   // (64+64) rows x 64 el
  const int tid = threadIdx.x, lane = tid & 63, w = tid >> 6;
  const int wR = w >> 1, wC = w & 1;
  const int lr = lane & 15, lk = lane >> 4;
  const int bm0 = blockIdx.y * 64, bn0 = blockIdx.x * 64;
  const int m0 = bm0 + wR * 32, n0 = bn0 + wC * 32;
  const u16* A = p.A;
  const u16* B = (MODE == 6 && bn0 >= 1024) ? (p.B2 - 1048576) : p.B;

  f32x4 acc[2][2] = {};

  auto stage = [&](int k0, int buf) {   // 4 x gload16 per thread
#pragma unroll
    for (int i = 0; i < 4; ++i) {
      const int c = i * 256 + w * 64 + lane;
      const int row = c >> 3;                       // tile row (A: 0..63, B: 64..127)
      const int col = ((c & 7) ^ (row & 7)) * 8;    // pre-swizzled source column
      const u16* g;
      if (row < 64) {
        g = A + (long)(bm0 + row) * p.ldA + k0 + col;
      } else {
        g = B + (long)(bn0 + (row - 64)) * p.ldB + k0 + col;
      }
      gload16(g, &sm[buf][(size_t)c * 8]);
    }
  };

  auto compute = [&](int buf) {
    const u16* As = sm[buf];
    const u16* Bs = sm[buf] + 4096;
    short8 af[2][2], bf[2][2];
#pragma unroll
    for (int mi = 0; mi < 2; ++mi)
#pragma unroll
      for (int kk = 0; kk < 2; ++kk) {
        af[mi][kk] = read8sw(As, (wR * 2 + mi) * 16 + lr, kk * 32 + lk * 8);
        bf[mi][kk] = read8sw(Bs, (wC * 2 + mi) * 16 + lr, kk * 32 + lk * 8);
      }
#pragma unroll
    for (int kk = 0; kk < 2; ++kk)
#pragma unroll
      for (int mi = 0; mi < 2; ++mi)
#pragma unroll
        for (int ni = 0; ni < 2; ++ni)
          acc[mi][ni] = __builtin_amdgcn_mfma_f32_16x16x32_bf16(af[mi][kk], bf[ni][kk], acc[mi][ni], 0, 0, 0);
  };

  const int nt = p.K / 64;
  stage(0, 0);
  stage(64, 1);
  for (int t = 0; t < nt; ++t) {
    if (t < nt - 1) wait_vm4(); else wait_vm0();   // my tile-t loads done
    __builtin_amdgcn_s_barrier();                  // all waves' tile-t loads done
    compute(t & 1);
    wait_lgkm0();                                  // my ds_reads landed in regs
    __builtin_amdgcn_s_barrier();                  // all waves done reading buf
    if (t + 2 < nt) stage((t + 2) * 64, t & 1);    // overwrite freed buffer
  }

#pragma unroll
  for (int mi = 0; mi < 2; ++mi)
#pragma unroll
    for (int ni = 0; ni < 2; ++ni)
#pragma unroll
      for (int r = 0; r < 4; ++r) {
        int row = m0 + mi * 16 + lk * 4 + r;   // C/D: row=(lane>>4)*4+reg
        int col = n0 + ni * 16 + lr;           //      col=lane&15
        float v = acc[mi][ni][r];
        if constexpr (MODE == 6) {
          if (col < 1024) {
            p.ob[(long)row * 1024 + col] = f2b(v);
          } else if (col < 2048) {
            p.ob2[(long)row * 1024 + (col - 1024)] = f2b(v);
          } else {
            int c = col - 2048, n = c >> 6, dd = c & 63, s = row >> 1, b = row & 1;
            p.aux_b16[(((long)((b * kN + n) * kDH + dd)) << 10) + permS(s)] = f2b(v);
          }
        } else {
          p.of[(long)row * p.ldO + col] = v;
        }
      }
}

// ---------------- fused twicing attention (flash, counted-vmcnt pipeline) ----------------
// Per (z, q-block of 64): wave w owns q-rows q0=w*16..+16. Per K-tile j (64 keys):
//   S^T via mfma(K, Qfrag) -> lane holds P[q=lr][k=kt*16+lk*4+r] ;
//   exp2(s*c) -> pack bf16 in REGISTERS -> directly the PV A-frag (B operand layouts
//   are k-permuted via permS at write time) ; acc += P * Btile.
// PASS1 (bp=v^T): writes normalized U^T (permuted) + linv. PASS2 (bp=U^T):
// vec = 2*U - (P@U)*linv.
template <bool PASS1>
__global__ __launch_bounds__(256, 4) void flash_tw(const u16* __restrict__ qp,
                                                   const u16* __restrict__ kp,
                                                   const u16* __restrict__ bp,
                                                   float* __restrict__ linv_g,
                                                   u16* __restrict__ outp) {
  __shared__ __align__(16) u16 Ks[2][64 * 64];   // 16 KB
  __shared__ __align__(16) u16 Bs[2][64 * 64];   // 16 KB
  __shared__ float lred[64], lrinv[64];
  const int z = blockIdx.y, qb0 = blockIdx.x * 64;
  const int tid = threadIdx.x, lane = tid & 63, w = tid >> 6;
  const int lr = lane & 15, lk = lane >> 4;
  const int q0 = w * 16;

  // Q fragments first (oldest vmem ops; compiler waits stay loose): Q[q0+lr][dh]
  short8 qf[2];
#pragma unroll
  for (int kk = 0; kk < 2; ++kk)
    qf[kk] = *(const short8*)(qp + (long)(qb0 + q0 + lr) * 2048 + z * 64 + kk * 32 + lk * 8);

  auto stageKB = [&](int j, int buf) {   // 4 x gload16 per thread
#pragma unroll
    for (int i = 0; i < 2; ++i) {
      int c = i * 256 + w * 64 + lane;
      int row = c >> 3, col = (c & 7) ^ (row & 7);
      gload16(kp + (long)(j * 64 + row) * 2048 + z * 64 + col * 8, Ks[buf] + c * 8);
      gload16(bp + (long)z * 65536 + (long)row * 1024 + j * 64 + col * 8, Bs[buf] + c * 8);
    }
  };
  stageKB(0, 0);
  stageKB(1, 1);

  f32x4 acc[4] = {};
  float lsum = 0.f;

  for (int j = 0; j < 16; ++j) {
    const int cur = j & 1;
    if (j < 15) wait_vm4(); else wait_vm0();   // my tile-j loads done (j+1 stays in flight)
    __builtin_amdgcn_s_barrier();              // all waves' tile-j loads done
    // S^T phase: st[kt] covers k = kt*16.., q = q0.. (this wave's rows)
    f32x4 st[4];
#pragma unroll
    for (int kt = 0; kt < 4; ++kt) st[kt] = (f32x4){0.f, 0.f, 0.f, 0.f};
#pragma unroll
    for (int kk = 0; kk < 2; ++kk)
#pragma unroll
      for (int kt = 0; kt < 4; ++kt) {
        short8 kf = read8sw(Ks[cur], kt * 16 + lr, kk * 32 + lk * 8);
        st[kt] = __builtin_amdgcn_mfma_f32_16x16x32_bf16(kf, qf[kk], st[kt], 0, 0, 0);
      }
    // exp2(score * 0.125*log2e) -> bf16 pack (lane: q=lr, k=kt*16+lk*4+{0..3})
    uint2 pk[4];
#pragma unroll
    for (int kt = 0; kt < 4; ++kt) {
      float e0 = exp2f(st[kt][0] * kExp2Scale);
      float e1 = exp2f(st[kt][1] * kExp2Scale);
      float e2 = exp2f(st[kt][2] * kExp2Scale);
      float e3 = exp2f(st[kt][3] * kExp2Scale);
      if (PASS1) lsum += e0 + e1 + e2 + e3;
      pk[kt].x = (u32)f2b(e0) | ((u32)f2b(e1) << 16);
      pk[kt].y = (u32)f2b(e2) | ((u32)f2b(e3) << 16);
    }
    // U phase: acc[dt] += P * Btile ; P-frag = pk pair (permuted-k A-frag)
#pragma unroll
    for (int kk = 0; kk < 2; ++kk) {
      union { u32 u[4]; short8 s8; } pa;
      pa.u[0] = pk[kk * 2].x; pa.u[1] = pk[kk * 2].y;
      pa.u[2] = pk[kk * 2 + 1].x; pa.u[3] = pk[kk * 2 + 1].y;
#pragma unroll
      for (int dt = 0; dt < 4; ++dt) {
        short8 bf = read8sw(Bs[cur], dt * 16 + lr, kk * 32 + lk * 8);
        acc[dt] = __builtin_amdgcn_mfma_f32_16x16x32_bf16(pa.s8, bf, acc[dt], 0, 0, 0);
      }
    }
    wait_lgkm0();                              // my ds_reads landed in regs
    __builtin_amdgcn_s_barrier();              // all waves done reading buf cur
    if (j < 14) stageKB(j + 2, cur);           // overwrite freed buffer
  }

  float iv[4];
  if (PASS1) {
    lsum += __shfl_xor(lsum, 16);
    lsum += __shfl_xor(lsum, 32);
    if (lane < 16) lred[q0 + lr] = lsum;
    __syncthreads();
    if (tid < 64) {
      float v = 1.f / lred[tid];
      lrinv[tid] = v;
      linv_g[(long)z * 1024 + qb0 + tid] = v;
    }
    __syncthreads();
#pragma unroll
    for (int r = 0; r < 4; ++r) iv[r] = lrinv[q0 + lk * 4 + r];
  } else {
    float4 l4 = *(const float4*)(linv_g + (long)z * 1024 + qb0 + q0 + lk * 4);
    iv[0] = l4.x; iv[1] = l4.y; iv[2] = l4.z; iv[3] = l4.w;
  }

  const int sq = qb0 + q0 + lk * 4;            // true q of acc rows (aligned 4)
  const int sp = (sq & ~31) + ((sq & 12) << 1) + ((sq & 16) >> 2);  // permuted base
#pragma unroll
  for (int dt = 0; dt < 4; ++dt) {
    const int d = dt * 16 + lr;                // C/D col
    if (PASS1) {
      uint2 o_;
      o_.x = (u32)f2b(acc[dt][0] * iv[0]) | ((u32)f2b(acc[dt][1] * iv[1]) << 16);
      o_.y = (u32)f2b(acc[dt][2] * iv[2]) | ((u32)f2b(acc[dt][3] * iv[3]) << 16);
      *(uint2*)(outp + (long)z * 65536 + (long)d * 1024 + sp) = o_;
    } else {
      uint2 ut = *(const uint2*)(bp + (long)z * 65536 + (long)d * 1024 + sp);
      float u0 = b2f(ut.x & 0xffffu), u1 = b2f(ut.x >> 16);
      float u2 = b2f(ut.y & 0xffffu), u3 = b2f(ut.y >> 16);
      long ob = (long)sq * 2048 + z * 64 + d;
      outp[ob]        = f2b(2.f * u0 - acc[dt][0] * iv[0]);
      outp[ob + 2048] = f2b(2.f * u1 - acc[dt][1] * iv[1]);
      outp[ob + 4096] = f2b(2.f * u2 - acc[dt][2] * iv[2]);
      outp[ob + 6144] = f2b(2.f * u3 - acc[dt][3] * iv[3]);
    }
  }
}

// ---------------- residual + LayerNorm ----------------
__global__ __launch_bounds__(256) void resid_ln(const float* __restrict__ h,
                                                const float* __restrict__ attn,
                                                const float* __restrict__ gamma,
                                                const float* __restrict__ beta,
                                                float* __restrict__ out) {
  __shared__ float rs[4], rs2[4];
  const long row = blockIdx.x;
  const int t = threadIdx.x;
  long base = (row << 10) + t * 4;
  float4 hv = *(const float4*)(h + base);
  float4 av = *(const float4*)(attn + base);
  float x0 = hv.x + av.x, x1 = hv.y + av.y, x2 = hv.z + av.z, x3 = hv.w + av.w;
  float s = x0 + x1 + x2 + x3;
  float s2 = x0 * x0 + x1 * x1 + x2 * x2 + x3 * x3;
  for (int o = 32; o; o >>= 1) { s += __shfl_xor(s, o); s2 += __shfl_xor(s2, o); }
  int wid = t >> 6;
  if ((t & 63) == 0) { rs[wid] = s; rs2[wid] = s2; }
  __syncthreads();
  s = rs[0] + rs[1] + rs[2] + rs[3];
  s2 = rs2[0] + rs2[1] + rs2[2] + rs2[3];
  float mean = s * (1.f / 1024.f);
  float var = s2 * (1.f / 1024.f) - mean * mean;
  float rstd = rsqrtf(var + kEps);
  int d = t * 4;
  float4 g = *(const float4*)(gamma + d);
  float4 bt = *(const float4*)(beta + d);
  float4 o_;
  o_.x = (x0 - mean) * rstd * g.x + bt.x;
  o_.y = (x1 - mean) * rstd * g.y + bt.y;
  o_.z = (x2 - mean) * rstd * g.z + bt.z;
  o_.w = (x3 - mean) * rstd * g.w + bt.w;
  *(float4*)(out + base) = o_;
}

extern "C" void kernel_launch(void* const* d_in, const int* in_sizes, int n_in,
                              void* d_out, int out_size, void* d_ws, size_t ws_size,
                              hipStream_t stream) {
  const float* h = (const float*)d_in[0];
  const float* Wq = (const float*)d_in[1];
  const float* Wkv = (const float*)d_in[2];
  const float* Wo = (const float*)d_in[3];
  const float* gamma = (const float*)d_in[4];
  const float* beta = (const float*)d_in[5];
  float* out = (float*)d_out;

  char* ws = (char*)d_ws;
  size_t off = 0;
  auto alloc = [&](size_t bytes) -> void* {
    void* p = ws + off;
    off = (off + bytes + 255) & ~(size_t)255;
    return p;
  };
  u16* hb = (u16*)alloc(2097152ULL * 2);
  u16* Wqb = (u16*)alloc(1048576ULL * 2);
  u16* Wkvb = (u16*)alloc(2097152ULL * 2);
  u16* Wob = (u16*)alloc(1048576ULL * 2);
  u16* qb = (u16*)alloc(2097152ULL * 2);      // [S, B*N*DH]
  u16* kb = (u16*)alloc(2097152ULL * 2);      // [S, B*N*DH]
  u16* vtb = (u16*)alloc(2097152ULL * 2);     // [B,N,DH,S-perm]
  u16* Ut = (u16*)alloc(2097152ULL * 2);      // [B,N,DH,S-perm] (normalized U^T)
  float* linv = (float*)alloc(32768ULL * 4);  // [B,N,S]
  u16* vecb = (u16*)alloc(2097152ULL * 2);    // [S, B*N*DH]
  float* attn = (float*)alloc(2097152ULL * 4);// [S,B,D]
  (void)ws_size; (void)n_in; (void)in_sizes; (void)out_size;

  // fused casts (h, Wq, Wkv, Wo)
  cvt_all<<<6144, 256, 0, stream>>>(h, Wq, Wkv, Wo, hb, Wqb, Wkvb, Wob);

  // fused qkv: [q | k | v^T-perm] = h @ [Wq;Wkv]^T  (M=2048, N=3072, K=1024)
  {
    GemmParams p{};
    p.A = hb; p.ldA = 1024;
    p.B = Wqb; p.ldB = 1024; p.B2 = Wkvb;
    p.K = 1024; p.ob = qb; p.ob2 = kb; p.aux_b16 = vtb;
    gemm_tile<6><<<dim3(48, 32, 1), 256, 0, stream>>>(p);
  }
  // flash pass 1: U = softmax(qk/8) @ V -> Ut (normalized, permuted) + linv
  flash_tw<true><<<dim3(16, 32), 256, 0, stream>>>(qb, kb, vtb, linv, Ut);
  // flash pass 2: vec = 2U - (P @ U) * linv -> vecb
  flash_tw<false><<<dim3(16, 32), 256, 0, stream>>>(qb, kb, Ut, linv, vecb);
  // attn = vec @ Wo^T  (M=2048, N=1024, K=1024), fp32 out; 64x64 tile (512 blocks)
  {
    GemmParams p{};
    p.A = vecb; p.ldA = 1024;
    p.B = Wob; p.ldB = 1024;
    p.K = 1024; p.of = attn; p.ldO = 1024;
    gemm_tile<5><<<dim3(16, 32, 1), 256, 0, stream>>>(p);
  }
  // out = LN(h + attn) * gamma + beta
  resid_ln<<<2048, 256, 0, stream>>>(h, attn, gamma, beta, out);
}

// Round 12
// 94.699 us; speedup vs baseline: 1.0764x; 1.0016x over previous
//
#include <hip/hip_runtime.h>

typedef unsigned short u16;
typedef unsigned int u32;
typedef __attribute__((ext_vector_type(8))) short short8;
typedef __attribute__((ext_vector_type(4))) float f32x4;

constexpr int kN = 16, kDH = 64, kD = 1024;
constexpr float kEps = 1e-5f;
constexpr float kExp2Scale = 0.18033688011112042f;   // 0.125 * log2(e)

__device__ __forceinline__ u16 f2b(float f) {
  u32 u = __float_as_uint(f);
  u += 0x7fffu + ((u >> 16) & 1u);   // round-to-nearest-even bf16
  return (u16)(u >> 16);
}
__device__ __forceinline__ float b2f(u32 bits) {
  return __uint_as_float(bits << 16);
}

// 16B direct global->LDS DMA. LDS dest is wave-uniform base + lane*16 (HW rule).
__device__ __forceinline__ void gload16(const u16* g, u16* l) {
  __builtin_amdgcn_global_load_lds(
      (const __attribute__((address_space(1))) void*)g,
      (__attribute__((address_space(3))) void*)l, 16, 0, 0);
}

// Counted-vmcnt waits (T4): keep prefetch loads in flight across barriers.
__device__ __forceinline__ void wait_vm4() {
  asm volatile("s_waitcnt vmcnt(4)" ::: "memory");
  __builtin_amdgcn_sched_barrier(0);
}
__device__ __forceinline__ void wait_vm0() {
  asm volatile("s_waitcnt vmcnt(0)" ::: "memory");
  __builtin_amdgcn_sched_barrier(0);
}
__device__ __forceinline__ void wait_lgkm0() {
  asm volatile("s_waitcnt lgkmcnt(0)" ::: "memory");
  __builtin_amdgcn_sched_barrier(0);
}

// Swizzled read of a short8 frag from a [rows][64el] LDS tile whose SOURCE was
// pre-swizzled chunk-wise: el ^= ((row&7)<<3). colel must be a multiple of 8.
__device__ __forceinline__ short8 read8sw(const u16* base, int row, int colel) {
  return *(const short8*)(base + (row << 6) + (colel ^ ((row & 7) << 3)));
}

// k-permutation baked into v^T / U^T layouts so the in-register P (S^T C/D
// layout: lane lk holds k = t*16 + lk*4 + r) is directly a valid MFMA A-frag.
__device__ __forceinline__ int permS(int s) {
  return (s & ~31) + ((s & 12) << 1) + ((s & 16) >> 2) + (s & 3);
}

// ---------------- fused fp32 -> bf16 cast for all 4 tensors ----------------
__global__ __launch_bounds__(256) void cvt_all(const float* __restrict__ h,
                                               const float* __restrict__ wq,
                                               const float* __restrict__ wkv,
                                               const float* __restrict__ wo,
                                               u16* __restrict__ hb, u16* __restrict__ wqb,
                                               u16* __restrict__ wkvb, u16* __restrict__ wob) {
  long idx = (long)blockIdx.x * 256 + threadIdx.x;  // 4-element group index
  const float* in;
  u16* out;
  long base;
  if (idx < 524288L) { in = h; out = hb; base = idx; }
  else if (idx < 786432L) { in = wq; out = wqb; base = idx - 524288L; }
  else if (idx < 1310720L) { in = wkv; out = wkvb; base = idx - 786432L; }
  else { in = wo; out = wob; base = idx - 1310720L; }
  float4 v = *(const float4*)(in + base * 4);
  uint2 o;
  o.x = (u32)f2b(v.x) | ((u32)f2b(v.y) << 16);
  o.y = (u32)f2b(v.z) | ((u32)f2b(v.w) << 16);
  *(uint2*)(out + base * 4) = o;
}

// ---------------- tiled NT GEMM (projections), BK=64, T2-swizzled, T4-counted ----------------
struct GemmParams {
  const u16* A; long ldA;
  const u16* B; long ldB;
  const u16* B2;               // MODE6: Wkv
  int K;
  u16* ob; float* of; long ldO;
  u16* ob2;                    // MODE6: k out
  u16* aux_b16;                // MODE6: vtb (v transposed, k-permuted)
};

// MODE: 5=bf16 plain (attn), 6=fused qkv (q / k / v-transposed-permuted by col range)
// 64x64 tile, BK=64, double-buffered (32 KB LDS), 4 waves 2x2, 8 MFMA/wave/K-step.
// Counted-vmcnt pipeline: tile j+1 loads stay in flight across tile-j compute.
// T5: setprio(1) around the MFMA cluster (role-split waves exist under T4 pipeline).
template <int MODE>
__global__ __launch_bounds__(256) void gemm_tile(GemmParams p) {
  __shared__ __align__(16) u16 sm[2][8192];   // (64+64) rows x 64 el
  const int tid = threadIdx.x, lane = tid & 63, w = tid >> 6;
  const int wR = w >> 1, wC = w & 1;
  const int lr = lane & 15, lk = lane >> 4;
  const int bm0 = blockIdx.y * 64, bn0 = blockIdx.x * 64;
  const int m0 = bm0 + wR * 32, n0 = bn0 + wC * 32;
  const u16* A = p.A;
  const u16* B = (MODE == 6 && bn0 >= 1024) ? (p.B2 - 1048576) : p.B;

  f32x4 acc[2][2] = {};

  auto stage = [&](int k0, int buf) {   // 4 x gload16 per thread
#pragma unroll
    for (int i = 0; i < 4; ++i) {
      const int c = i * 256 + w * 64 + lane;
      const int row = c >> 3;                       // tile row (A: 0..63, B: 64..127)
      const int col = ((c & 7) ^ (row & 7)) * 8;    // pre-swizzled source column
      const u16* g;
      if (row < 64) {
        g = A + (long)(bm0 + row) * p.ldA + k0 + col;
      } else {
        g = B + (long)(bn0 + (row - 64)) * p.ldB + k0 + col;
      }
      gload16(g, &sm[buf][(size_t)c * 8]);
    }
  };

  auto compute = [&](int buf) {
    const u16* As = sm[buf];
    const u16* Bs = sm[buf] + 4096;
    short8 af[2][2], bf[2][2];
#pragma unroll
    for (int mi = 0; mi < 2; ++mi)
#pragma unroll
      for (int kk = 0; kk < 2; ++kk) {
        af[mi][kk] = read8sw(As, (wR * 2 + mi) * 16 + lr, kk * 32 + lk * 8);
        bf[mi][kk] = read8sw(Bs, (wC * 2 + mi) * 16 + lr, kk * 32 + lk * 8);
      }
    __builtin_amdgcn_s_setprio(1);
#pragma unroll
    for (int kk = 0; kk < 2; ++kk)
#pragma unroll
      for (int mi = 0; mi < 2; ++mi)
#pragma unroll
        for (int ni = 0; ni < 2; ++ni)
          acc[mi][ni] = __builtin_amdgcn_mfma_f32_16x16x32_bf16(af[mi][kk], bf[ni][kk], acc[mi][ni], 0, 0, 0);
    __builtin_amdgcn_s_setprio(0);
  };

  const int nt = p.K / 64;
  stage(0, 0);
  stage(64, 1);
  for (int t = 0; t < nt; ++t) {
    if (t < nt - 1) wait_vm4(); else wait_vm0();   // my tile-t loads done
    __builtin_amdgcn_s_barrier();                  // all waves' tile-t loads done
    compute(t & 1);
    wait_lgkm0();                                  // my ds_reads landed in regs
    __builtin_amdgcn_s_barrier();                  // all waves done reading buf
    if (t + 2 < nt) stage((t + 2) * 64, t & 1);    // overwrite freed buffer
  }

#pragma unroll
  for (int mi = 0; mi < 2; ++mi)
#pragma unroll
    for (int ni = 0; ni < 2; ++ni)
#pragma unroll
      for (int r = 0; r < 4; ++r) {
        int row = m0 + mi * 16 + lk * 4 + r;   // C/D: row=(lane>>4)*4+reg
        int col = n0 + ni * 16 + lr;           //      col=lane&15
        float v = acc[mi][ni][r];
        if constexpr (MODE == 6) {
          if (col < 1024) {
            p.ob[(long)row * 1024 + col] = f2b(v);
          } else if (col < 2048) {
            p.ob2[(long)row * 1024 + (col - 1024)] = f2b(v);
          } else {
            int c = col - 2048, n = c >> 6, dd = c & 63, s = row >> 1, b = row & 1;
            p.aux_b16[(((long)((b * kN + n) * kDH + dd)) << 10) + permS(s)] = f2b(v);
          }
        } else {
          p.ob[(long)row * p.ldO + col] = f2b(v);
        }
      }
}

// ---------------- fused twicing attention (flash, counted-vmcnt pipeline) ----------------
// Per (z, q-block of 64): wave w owns q-rows q0=w*16..+16. Per K-tile j (64 keys):
//   S^T via mfma(K, Qfrag) -> lane holds P[q=lr][k=kt*16+lk*4+r] ;
//   exp2(s*c) -> pack bf16 in REGISTERS -> directly the PV A-frag (B operand layouts
//   are k-permuted via permS at write time) ; acc += P * Btile.
// PASS1 (bp=v^T): writes normalized U^T (permuted) + linv. PASS2 (bp=U^T):
// vec = 2*U - (P@U)*linv.
template <bool PASS1>
__global__ __launch_bounds__(256, 4) void flash_tw(const u16* __restrict__ qp,
                                                   const u16* __restrict__ kp,
                                                   const u16* __restrict__ bp,
                                                   float* __restrict__ linv_g,
                                                   u16* __restrict__ outp) {
  __shared__ __align__(16) u16 Ks[2][64 * 64];   // 16 KB
  __shared__ __align__(16) u16 Bs[2][64 * 64];   // 16 KB
  __shared__ float lred[64], lrinv[64];
  const int z = blockIdx.y, qb0 = blockIdx.x * 64;
  const int tid = threadIdx.x, lane = tid & 63, w = tid >> 6;
  const int lr = lane & 15, lk = lane >> 4;
  const int q0 = w * 16;

  // Q fragments first (oldest vmem ops; compiler waits stay loose): Q[q0+lr][dh]
  short8 qf[2];
#pragma unroll
  for (int kk = 0; kk < 2; ++kk)
    qf[kk] = *(const short8*)(qp + (long)(qb0 + q0 + lr) * 2048 + z * 64 + kk * 32 + lk * 8);

  auto stageKB = [&](int j, int buf) {   // 4 x gload16 per thread
#pragma unroll
    for (int i = 0; i < 2; ++i) {
      int c = i * 256 + w * 64 + lane;
      int row = c >> 3, col = (c & 7) ^ (row & 7);
      gload16(kp + (long)(j * 64 + row) * 2048 + z * 64 + col * 8, Ks[buf] + c * 8);
      gload16(bp + (long)z * 65536 + (long)row * 1024 + j * 64 + col * 8, Bs[buf] + c * 8);
    }
  };
  stageKB(0, 0);
  stageKB(1, 1);

  f32x4 acc[4] = {};
  float lsum = 0.f;

  for (int j = 0; j < 16; ++j) {
    const int cur = j & 1;
    if (j < 15) wait_vm4(); else wait_vm0();   // my tile-j loads done (j+1 stays in flight)
    __builtin_amdgcn_s_barrier();              // all waves' tile-j loads done
    // S^T phase: st[kt] covers k = kt*16.., q = q0.. (this wave's rows)
    f32x4 st[4];
#pragma unroll
    for (int kt = 0; kt < 4; ++kt) st[kt] = (f32x4){0.f, 0.f, 0.f, 0.f};
#pragma unroll
    for (int kk = 0; kk < 2; ++kk) {
      short8 kf0 = read8sw(Ks[cur], 0 * 16 + lr, kk * 32 + lk * 8);
      short8 kf1 = read8sw(Ks[cur], 1 * 16 + lr, kk * 32 + lk * 8);
      short8 kf2 = read8sw(Ks[cur], 2 * 16 + lr, kk * 32 + lk * 8);
      short8 kf3 = read8sw(Ks[cur], 3 * 16 + lr, kk * 32 + lk * 8);
      __builtin_amdgcn_s_setprio(1);
      st[0] = __builtin_amdgcn_mfma_f32_16x16x32_bf16(kf0, qf[kk], st[0], 0, 0, 0);
      st[1] = __builtin_amdgcn_mfma_f32_16x16x32_bf16(kf1, qf[kk], st[1], 0, 0, 0);
      st[2] = __builtin_amdgcn_mfma_f32_16x16x32_bf16(kf2, qf[kk], st[2], 0, 0, 0);
      st[3] = __builtin_amdgcn_mfma_f32_16x16x32_bf16(kf3, qf[kk], st[3], 0, 0, 0);
      __builtin_amdgcn_s_setprio(0);
    }
    // exp2(score * 0.125*log2e) -> bf16 pack (lane: q=lr, k=kt*16+lk*4+{0..3})
    uint2 pk[4];
#pragma unroll
    for (int kt = 0; kt < 4; ++kt) {
      float e0 = exp2f(st[kt][0] * kExp2Scale);
      float e1 = exp2f(st[kt][1] * kExp2Scale);
      float e2 = exp2f(st[kt][2] * kExp2Scale);
      float e3 = exp2f(st[kt][3] * kExp2Scale);
      if (PASS1) lsum += e0 + e1 + e2 + e3;
      pk[kt].x = (u32)f2b(e0) | ((u32)f2b(e1) << 16);
      pk[kt].y = (u32)f2b(e2) | ((u32)f2b(e3) << 16);
    }
    // U phase: acc[dt] += P * Btile ; P-frag = pk pair (permuted-k A-frag)
#pragma unroll
    for (int kk = 0; kk < 2; ++kk) {
      union { u32 u[4]; short8 s8; } pa;
      pa.u[0] = pk[kk * 2].x; pa.u[1] = pk[kk * 2].y;
      pa.u[2] = pk[kk * 2 + 1].x; pa.u[3] = pk[kk * 2 + 1].y;
      short8 bf0 = read8sw(Bs[cur], 0 * 16 + lr, kk * 32 + lk * 8);
      short8 bf1 = read8sw(Bs[cur], 1 * 16 + lr, kk * 32 + lk * 8);
      short8 bf2 = read8sw(Bs[cur], 2 * 16 + lr, kk * 32 + lk * 8);
      short8 bf3 = read8sw(Bs[cur], 3 * 16 + lr, kk * 32 + lk * 8);
      __builtin_amdgcn_s_setprio(1);
      acc[0] = __builtin_amdgcn_mfma_f32_16x16x32_bf16(pa.s8, bf0, acc[0], 0, 0, 0);
      acc[1] = __builtin_amdgcn_mfma_f32_16x16x32_bf16(pa.s8, bf1, acc[1], 0, 0, 0);
      acc[2] = __builtin_amdgcn_mfma_f32_16x16x32_bf16(pa.s8, bf2, acc[2], 0, 0, 0);
      acc[3] = __builtin_amdgcn_mfma_f32_16x16x32_bf16(pa.s8, bf3, acc[3], 0, 0, 0);
      __builtin_amdgcn_s_setprio(0);
    }
    wait_lgkm0();                              // my ds_reads landed in regs
    __builtin_amdgcn_s_barrier();              // all waves done reading buf cur
    if (j < 14) stageKB(j + 2, cur);           // overwrite freed buffer
  }

  float iv[4];
  if (PASS1) {
    lsum += __shfl_xor(lsum, 16);
    lsum += __shfl_xor(lsum, 32);
    if (lane < 16) lred[q0 + lr] = lsum;
    __syncthreads();
    if (tid < 64) {
      float v = 1.f / lred[tid];
      lrinv[tid] = v;
      linv_g[(long)z * 1024 + qb0 + tid] = v;
    }
    __syncthreads();
#pragma unroll
    for (int r = 0; r < 4; ++r) iv[r] = lrinv[q0 + lk * 4 + r];
  } else {
    float4 l4 = *(const float4*)(linv_g + (long)z * 1024 + qb0 + q0 + lk * 4);
    iv[0] = l4.x; iv[1] = l4.y; iv[2] = l4.z; iv[3] = l4.w;
  }

  const int sq = qb0 + q0 + lk * 4;            // true q of acc rows (aligned 4)
  const int sp = (sq & ~31) + ((sq & 12) << 1) + ((sq & 16) >> 2);  // permuted base
#pragma unroll
  for (int dt = 0; dt < 4; ++dt) {
    const int d = dt * 16 + lr;                // C/D col
    if (PASS1) {
      uint2 o_;
      o_.x = (u32)f2b(acc[dt][0] * iv[0]) | ((u32)f2b(acc[dt][1] * iv[1]) << 16);
      o_.y = (u32)f2b(acc[dt][2] * iv[2]) | ((u32)f2b(acc[dt][3] * iv[3]) << 16);
      *(uint2*)(outp + (long)z * 65536 + (long)d * 1024 + sp) = o_;
    } else {
      uint2 ut = *(const uint2*)(bp + (long)z * 65536 + (long)d * 1024 + sp);
      float u0 = b2f(ut.x & 0xffffu), u1 = b2f(ut.x >> 16);
      float u2 = b2f(ut.y & 0xffffu), u3 = b2f(ut.y >> 16);
      long ob = (long)sq * 2048 + z * 64 + d;
      outp[ob]        = f2b(2.f * u0 - acc[dt][0] * iv[0]);
      outp[ob + 2048] = f2b(2.f * u1 - acc[dt][1] * iv[1]);
      outp[ob + 4096] = f2b(2.f * u2 - acc[dt][2] * iv[2]);
      outp[ob + 6144] = f2b(2.f * u3 - acc[dt][3] * iv[3]);
    }
  }
}

// ---------------- residual + LayerNorm (attn in bf16) ----------------
__global__ __launch_bounds__(256) void resid_ln(const float* __restrict__ h,
                                                const u16* __restrict__ attnb,
                                                const float* __restrict__ gamma,
                                                const float* __restrict__ beta,
                                                float* __restrict__ out) {
  __shared__ float rs[4], rs2[4];
  const long row = blockIdx.x;
  const int t = threadIdx.x;
  long base = (row << 10) + t * 4;
  float4 hv = *(const float4*)(h + base);
  uint2 av = *(const uint2*)(attnb + base);
  float a0 = b2f(av.x & 0xffffu), a1 = b2f(av.x >> 16);
  float a2 = b2f(av.y & 0xffffu), a3 = b2f(av.y >> 16);
  float x0 = hv.x + a0, x1 = hv.y + a1, x2 = hv.z + a2, x3 = hv.w + a3;
  float s = x0 + x1 + x2 + x3;
  float s2 = x0 * x0 + x1 * x1 + x2 * x2 + x3 * x3;
  for (int o = 32; o; o >>= 1) { s += __shfl_xor(s, o); s2 += __shfl_xor(s2, o); }
  int wid = t >> 6;
  if ((t & 63) == 0) { rs[wid] = s; rs2[wid] = s2; }
  __syncthreads();
  s = rs[0] + rs[1] + rs[2] + rs[3];
  s2 = rs2[0] + rs2[1] + rs2[2] + rs2[3];
  float mean = s * (1.f / 1024.f);
  float var = s2 * (1.f / 1024.f) - mean * mean;
  float rstd = rsqrtf(var + kEps);
  int d = t * 4;
  float4 g = *(const float4*)(gamma + d);
  float4 bt = *(const float4*)(beta + d);
  float4 o_;
  o_.x = (x0 - mean) * rstd * g.x + bt.x;
  o_.y = (x1 - mean) * rstd * g.y + bt.y;
  o_.z = (x2 - mean) * rstd * g.z + bt.z;
  o_.w = (x3 - mean) * rstd * g.w + bt.w;
  *(float4*)(out + base) = o_;
}

extern "C" void kernel_launch(void* const* d_in, const int* in_sizes, int n_in,
                              void* d_out, int out_size, void* d_ws, size_t ws_size,
                              hipStream_t stream) {
  const float* h = (const float*)d_in[0];
  const float* Wq = (const float*)d_in[1];
  const float* Wkv = (const float*)d_in[2];
  const float* Wo = (const float*)d_in[3];
  const float* gamma = (const float*)d_in[4];
  const float* beta = (const float*)d_in[5];
  float* out = (float*)d_out;

  char* ws = (char*)d_ws;
  size_t off = 0;
  auto alloc = [&](size_t bytes) -> void* {
    void* p = ws + off;
    off = (off + bytes + 255) & ~(size_t)255;
    return p;
  };
  u16* hb = (u16*)alloc(2097152ULL * 2);
  u16* Wqb = (u16*)alloc(1048576ULL * 2);
  u16* Wkvb = (u16*)alloc(2097152ULL * 2);
  u16* Wob = (u16*)alloc(1048576ULL * 2);
  u16* qb = (u16*)alloc(2097152ULL * 2);      // [S, B*N*DH]
  u16* kb = (u16*)alloc(2097152ULL * 2);      // [S, B*N*DH]
  u16* vtb = (u16*)alloc(2097152ULL * 2);     // [B,N,DH,S-perm]
  u16* Ut = (u16*)alloc(2097152ULL * 2);      // [B,N,DH,S-perm] (normalized U^T)
  float* linv = (float*)alloc(32768ULL * 4);  // [B,N,S]
  u16* vecb = (u16*)alloc(2097152ULL * 2);    // [S, B*N*DH]
  u16* attnb = (u16*)alloc(2097152ULL * 2);   // [S,B,D] bf16
  (void)ws_size; (void)n_in; (void)in_sizes; (void)out_size;

  // fused casts (h, Wq, Wkv, Wo)
  cvt_all<<<6144, 256, 0, stream>>>(h, Wq, Wkv, Wo, hb, Wqb, Wkvb, Wob);

  // fused qkv: [q | k | v^T-perm] = h @ [Wq;Wkv]^T  (M=2048, N=3072, K=1024)
  {
    GemmParams p{};
    p.A = hb; p.ldA = 1024;
    p.B = Wqb; p.ldB = 1024; p.B2 = Wkvb;
    p.K = 1024; p.ob = qb; p.ob2 = kb; p.aux_b16 = vtb;
    gemm_tile<6><<<dim3(48, 32, 1), 256, 0, stream>>>(p);
  }
  // flash pass 1: U = softmax(qk/8) @ V -> Ut (normalized, permuted) + linv
  flash_tw<true><<<dim3(16, 32), 256, 0, stream>>>(qb, kb, vtb, linv, Ut);
  // flash pass 2: vec = 2U - (P @ U) * linv -> vecb
  flash_tw<false><<<dim3(16, 32), 256, 0, stream>>>(qb, kb, Ut, linv, vecb);
  // attn = vec @ Wo^T  (M=2048, N=1024, K=1024), bf16 out; 64x64 tile (512 blocks)
  {
    GemmParams p{};
    p.A = vecb; p.ldA = 1024;
    p.B = Wob; p.ldB = 1024;
    p.K = 1024; p.ob = attnb; p.ldO = 1024;
    gemm_tile<5><<<dim3(16, 32, 1), 256, 0, stream>>>(p);
  }
  // out = LN(h + attn) * gamma + beta
  resid_ln<<<2048, 256, 0, stream>>>(h, attnb, gamma, beta, out);
}

// Round 13
// 92.618 us; speedup vs baseline: 1.1006x; 1.0225x over previous
//
#include <hip/hip_runtime.h>

typedef unsigned short u16;
typedef unsigned int u32;
typedef __attribute__((ext_vector_type(8))) short short8;
typedef __attribute__((ext_vector_type(4))) float f32x4;

constexpr int kN = 16, kDH = 64, kD = 1024;
constexpr float kEps = 1e-5f;
constexpr float kExp2Scale = 0.18033688011112042f;   // 0.125 * log2(e)

__device__ __forceinline__ u16 f2b(float f) {
  u32 u = __float_as_uint(f);
  u += 0x7fffu + ((u >> 16) & 1u);   // round-to-nearest-even bf16
  return (u16)(u >> 16);
}
__device__ __forceinline__ float b2f(u32 bits) {
  return __uint_as_float(bits << 16);
}

// 16B direct global->LDS DMA. LDS dest is wave-uniform base + lane*16 (HW rule).
__device__ __forceinline__ void gload16(const u16* g, u16* l) {
  __builtin_amdgcn_global_load_lds(
      (const __attribute__((address_space(1))) void*)g,
      (__attribute__((address_space(3))) void*)l, 16, 0, 0);
}

// Counted-vmcnt waits (T4): keep prefetch loads in flight across barriers.
template <int N>
__device__ __forceinline__ void wait_vmN() {
  if constexpr (N == 0) asm volatile("s_waitcnt vmcnt(0)" ::: "memory");
  else if constexpr (N == 4) asm volatile("s_waitcnt vmcnt(4)" ::: "memory");
  else if constexpr (N == 7) asm volatile("s_waitcnt vmcnt(7)" ::: "memory");
  else static_assert(N == 0 || N == 4 || N == 7, "add literal");
  __builtin_amdgcn_sched_barrier(0);
}
__device__ __forceinline__ void wait_lgkm0() {
  asm volatile("s_waitcnt lgkmcnt(0)" ::: "memory");
  __builtin_amdgcn_sched_barrier(0);
}

// Swizzled read of a short8 frag from a [rows][64el] LDS tile whose SOURCE was
// pre-swizzled chunk-wise: el ^= ((row&7)<<3). colel must be a multiple of 8.
__device__ __forceinline__ short8 read8sw(const u16* base, int row, int colel) {
  return *(const short8*)(base + (row << 6) + (colel ^ ((row & 7) << 3)));
}

// k-permutation baked into v^T / U^T layouts so the in-register P (S^T C/D
// layout: lane lk holds k = t*16 + lk*4 + r) is directly a valid MFMA A-frag.
__device__ __forceinline__ int permS(int s) {
  return (s & ~31) + ((s & 12) << 1) + ((s & 16) >> 2) + (s & 3);
}

// ---------------- fused fp32 -> bf16 cast for all 4 tensors ----------------
__global__ __launch_bounds__(256) void cvt_all(const float* __restrict__ h,
                                               const float* __restrict__ wq,
                                               const float* __restrict__ wkv,
                                               const float* __restrict__ wo,
                                               u16* __restrict__ hb, u16* __restrict__ wqb,
                                               u16* __restrict__ wkvb, u16* __restrict__ wob) {
  long idx = (long)blockIdx.x * 256 + threadIdx.x;  // 4-element group index
  const float* in;
  u16* out;
  long base;
  if (idx < 524288L) { in = h; out = hb; base = idx; }
  else if (idx < 786432L) { in = wq; out = wqb; base = idx - 524288L; }
  else if (idx < 1310720L) { in = wkv; out = wkvb; base = idx - 786432L; }
  else { in = wo; out = wob; base = idx - 1310720L; }
  float4 v = *(const float4*)(in + base * 4);
  uint2 o;
  o.x = (u32)f2b(v.x) | ((u32)f2b(v.y) << 16);
  o.y = (u32)f2b(v.z) | ((u32)f2b(v.w) << 16);
  *(uint2*)(out + base * 4) = o;
}

// ---------------- tiled NT GEMM, BK=64, T2-swizzled, T4-counted ----------------
struct GemmParams {
  const u16* A; long ldA;
  const u16* B; long ldB;   // MODE6: B = contiguous [Wq;Wkv] panel (3072 rows)
  int K;
  u16* ob; long ldO;
  u16* ob2;                 // MODE6: k out
  u16* aux_b16;             // MODE6: vtb (v transposed, k-permuted)
};

// MODE: 5=bf16 plain (attn), 6=fused qkv (q / k / v-transposed-permuted by col range)
// BM x BN tile, BK=64, double-buffered LDS; 4 waves (BM/(MF*16)) x (BN/(NF*16));
// wave computes (MF*16) x (NF*16) via 2*MF*NF mfma per K-step.
// Counted-vmcnt pipeline (T4) + setprio (T5) + chunk-XOR LDS swizzle (T2).
template <int MODE, int BM, int BN, int MF, int NF>
__global__ __launch_bounds__(256) void gemm_tile(GemmParams p) {
  constexpr int NLD = (BM + BN) / 32;   // 16B chunks per thread per tile
  constexpr int AIT = BM / 32;          // chunk-loop iterations staging A
  constexpr int WN = BN / (NF * 16);    // waves along N
  __shared__ __align__(16) u16 sm[2][(BM + BN) * 64];
  const int tid = threadIdx.x, lane = tid & 63, w = tid >> 6;
  const int wR = w / WN, wC = w % WN;
  const int lr = lane & 15, lk = lane >> 4;
  const int bm0 = blockIdx.y * BM, bn0 = blockIdx.x * BN;
  const int m0 = bm0 + wR * (MF * 16), n0 = bn0 + wC * (NF * 16);
  const u16* A = p.A;
  const u16* B = p.B;

  f32x4 acc[MF][NF] = {};

  auto stage = [&](int k0, int buf) {   // NLD x gload16 per thread
#pragma unroll
    for (int i = 0; i < NLD; ++i) {
      const int c = i * 256 + w * 64 + lane;
      const int row = c >> 3;                       // tile row (A: 0..BM-1, B: BM..)
      const int col = ((c & 7) ^ (row & 7)) * 8;    // pre-swizzled source column
      const u16* g;
      if (i < AIT) {
        g = A + (long)(bm0 + row) * p.ldA + k0 + col;
      } else {
        g = B + (long)(bn0 + (row - BM)) * p.ldB + k0 + col;
      }
      gload16(g, &sm[buf][(size_t)c * 8]);
    }
  };

  auto compute = [&](int buf) {
    const u16* As = sm[buf];
    const u16* Bs = sm[buf] + BM * 64;
    short8 af[MF][2], bf[NF][2];
#pragma unroll
    for (int mi = 0; mi < MF; ++mi)
#pragma unroll
      for (int kk = 0; kk < 2; ++kk)
        af[mi][kk] = read8sw(As, (wR * MF + mi) * 16 + lr, kk * 32 + lk * 8);
#pragma unroll
    for (int ni = 0; ni < NF; ++ni)
#pragma unroll
      for (int kk = 0; kk < 2; ++kk)
        bf[ni][kk] = read8sw(Bs, (wC * NF + ni) * 16 + lr, kk * 32 + lk * 8);
    __builtin_amdgcn_s_setprio(1);
#pragma unroll
    for (int kk = 0; kk < 2; ++kk)
#pragma unroll
      for (int mi = 0; mi < MF; ++mi)
#pragma unroll
        for (int ni = 0; ni < NF; ++ni)
          acc[mi][ni] = __builtin_amdgcn_mfma_f32_16x16x32_bf16(af[mi][kk], bf[ni][kk], acc[mi][ni], 0, 0, 0);
    __builtin_amdgcn_s_setprio(0);
  };

  const int nt = p.K / 64;
  stage(0, 0);
  stage(64, 1);
  for (int t = 0; t < nt; ++t) {
    if (t < nt - 1) wait_vmN<NLD>(); else wait_vmN<0>();   // my tile-t loads done
    __builtin_amdgcn_s_barrier();                          // all waves' tile-t loads done
    compute(t & 1);
    wait_lgkm0();                                          // my ds_reads landed
    __builtin_amdgcn_s_barrier();                          // all waves done reading buf
    if (t + 2 < nt) stage((t + 2) * 64, t & 1);            // overwrite freed buffer
  }

#pragma unroll
  for (int mi = 0; mi < MF; ++mi)
#pragma unroll
    for (int ni = 0; ni < NF; ++ni)
#pragma unroll
      for (int r = 0; r < 4; ++r) {
        int row = m0 + mi * 16 + lk * 4 + r;   // C/D: row=(lane>>4)*4+reg
        int col = n0 + ni * 16 + lr;           //      col=lane&15
        float v = acc[mi][ni][r];
        if constexpr (MODE == 6) {
          if (col < 1024) {
            p.ob[(long)row * 1024 + col] = f2b(v);
          } else if (col < 2048) {
            p.ob2[(long)row * 1024 + (col - 1024)] = f2b(v);
          } else {
            int c = col - 2048, n = c >> 6, dd = c & 63, s = row >> 1, b = row & 1;
            p.aux_b16[(((long)((b * kN + n) * kDH + dd)) << 10) + permS(s)] = f2b(v);
          }
        } else {
          p.ob[(long)row * p.ldO + col] = f2b(v);
        }
      }
}

// ---------------- fused twicing attention (flash, counted-vmcnt pipeline) ----------------
// Per (z, q-block of 64): wave w owns q-rows q0=w*16..+16. Per K-tile j (64 keys):
//   S^T via mfma(K, Qfrag) -> lane holds P[q=lr][k=kt*16+lk*4+r] ;
//   exp2(s*c) -> pack bf16 in REGISTERS -> directly the PV A-frag (B operand layouts
//   are k-permuted via permS at write time) ; acc += P * Btile.
// PASS1 (bp=v^T): writes normalized U^T (permuted) + linv. PASS2 (bp=U^T):
// vec = 2*U - (P@U)*linv.
template <bool PASS1>
__global__ __launch_bounds__(256, 4) void flash_tw(const u16* __restrict__ qp,
                                                   const u16* __restrict__ kp,
                                                   const u16* __restrict__ bp,
                                                   float* __restrict__ linv_g,
                                                   u16* __restrict__ outp) {
  __shared__ __align__(16) u16 Ks[2][64 * 64];   // 16 KB
  __shared__ __align__(16) u16 Bs[2][64 * 64];   // 16 KB
  __shared__ float lred[64], lrinv[64];
  const int z = blockIdx.y, qb0 = blockIdx.x * 64;
  const int tid = threadIdx.x, lane = tid & 63, w = tid >> 6;
  const int lr = lane & 15, lk = lane >> 4;
  const int q0 = w * 16;

  // Q fragments first (oldest vmem ops; compiler waits stay loose): Q[q0+lr][dh]
  short8 qf[2];
#pragma unroll
  for (int kk = 0; kk < 2; ++kk)
    qf[kk] = *(const short8*)(qp + (long)(qb0 + q0 + lr) * 2048 + z * 64 + kk * 32 + lk * 8);

  auto stageKB = [&](int j, int buf) {   // 4 x gload16 per thread
#pragma unroll
    for (int i = 0; i < 2; ++i) {
      int c = i * 256 + w * 64 + lane;
      int row = c >> 3, col = (c & 7) ^ (row & 7);
      gload16(kp + (long)(j * 64 + row) * 2048 + z * 64 + col * 8, Ks[buf] + c * 8);
      gload16(bp + (long)z * 65536 + (long)row * 1024 + j * 64 + col * 8, Bs[buf] + c * 8);
    }
  };
  stageKB(0, 0);
  stageKB(1, 1);

  f32x4 acc[4] = {};
  float lsum = 0.f;

  for (int j = 0; j < 16; ++j) {
    const int cur = j & 1;
    if (j < 15) wait_vmN<4>(); else wait_vmN<0>();   // tile-j loads done (j+1 in flight)
    __builtin_amdgcn_s_barrier();                    // all waves' tile-j loads done
    // S^T phase: st[kt] covers k = kt*16.., q = q0.. (this wave's rows)
    f32x4 st[4];
#pragma unroll
    for (int kt = 0; kt < 4; ++kt) st[kt] = (f32x4){0.f, 0.f, 0.f, 0.f};
#pragma unroll
    for (int kk = 0; kk < 2; ++kk) {
      short8 kf0 = read8sw(Ks[cur], 0 * 16 + lr, kk * 32 + lk * 8);
      short8 kf1 = read8sw(Ks[cur], 1 * 16 + lr, kk * 32 + lk * 8);
      short8 kf2 = read8sw(Ks[cur], 2 * 16 + lr, kk * 32 + lk * 8);
      short8 kf3 = read8sw(Ks[cur], 3 * 16 + lr, kk * 32 + lk * 8);
      __builtin_amdgcn_s_setprio(1);
      st[0] = __builtin_amdgcn_mfma_f32_16x16x32_bf16(kf0, qf[kk], st[0], 0, 0, 0);
      st[1] = __builtin_amdgcn_mfma_f32_16x16x32_bf16(kf1, qf[kk], st[1], 0, 0, 0);
      st[2] = __builtin_amdgcn_mfma_f32_16x16x32_bf16(kf2, qf[kk], st[2], 0, 0, 0);
      st[3] = __builtin_amdgcn_mfma_f32_16x16x32_bf16(kf3, qf[kk], st[3], 0, 0, 0);
      __builtin_amdgcn_s_setprio(0);
    }
    // exp2(score * 0.125*log2e) -> bf16 pack (lane: q=lr, k=kt*16+lk*4+{0..3})
    uint2 pk[4];
#pragma unroll
    for (int kt = 0; kt < 4; ++kt) {
      float e0 = exp2f(st[kt][0] * kExp2Scale);
      float e1 = exp2f(st[kt][1] * kExp2Scale);
      float e2 = exp2f(st[kt][2] * kExp2Scale);
      float e3 = exp2f(st[kt][3] * kExp2Scale);
      if (PASS1) lsum += e0 + e1 + e2 + e3;
      pk[kt].x = (u32)f2b(e0) | ((u32)f2b(e1) << 16);
      pk[kt].y = (u32)f2b(e2) | ((u32)f2b(e3) << 16);
    }
    // U phase: acc[dt] += P * Btile ; P-frag = pk pair (permuted-k A-frag)
#pragma unroll
    for (int kk = 0; kk < 2; ++kk) {
      union { u32 u[4]; short8 s8; } pa;
      pa.u[0] = pk[kk * 2].x; pa.u[1] = pk[kk * 2].y;
      pa.u[2] = pk[kk * 2 + 1].x; pa.u[3] = pk[kk * 2 + 1].y;
      short8 bf0 = read8sw(Bs[cur], 0 * 16 + lr, kk * 32 + lk * 8);
      short8 bf1 = read8sw(Bs[cur], 1 * 16 + lr, kk * 32 + lk * 8);
      short8 bf2 = read8sw(Bs[cur], 2 * 16 + lr, kk * 32 + lk * 8);
      short8 bf3 = read8sw(Bs[cur], 3 * 16 + lr, kk * 32 + lk * 8);
      __builtin_amdgcn_s_setprio(1);
      acc[0] = __builtin_amdgcn_mfma_f32_16x16x32_bf16(pa.s8, bf0, acc[0], 0, 0, 0);
      acc[1] = __builtin_amdgcn_mfma_f32_16x16x32_bf16(pa.s8, bf1, acc[1], 0, 0, 0);
      acc[2] = __builtin_amdgcn_mfma_f32_16x16x32_bf16(pa.s8, bf2, acc[2], 0, 0, 0);
      acc[3] = __builtin_amdgcn_mfma_f32_16x16x32_bf16(pa.s8, bf3, acc[3], 0, 0, 0);
      __builtin_amdgcn_s_setprio(0);
    }
    wait_lgkm0();                              // my ds_reads landed in regs
    __builtin_amdgcn_s_barrier();              // all waves done reading buf cur
    if (j < 14) stageKB(j + 2, cur);           // overwrite freed buffer
  }

  float iv[4];
  if (PASS1) {
    lsum += __shfl_xor(lsum, 16);
    lsum += __shfl_xor(lsum, 32);
    if (lane < 16) lred[q0 + lr] = lsum;
    __syncthreads();
    if (tid < 64) {
      float v = 1.f / lred[tid];
      lrinv[tid] = v;
      linv_g[(long)z * 1024 + qb0 + tid] = v;
    }
    __syncthreads();
#pragma unroll
    for (int r = 0; r < 4; ++r) iv[r] = lrinv[q0 + lk * 4 + r];
  } else {
    float4 l4 = *(const float4*)(linv_g + (long)z * 1024 + qb0 + q0 + lk * 4);
    iv[0] = l4.x; iv[1] = l4.y; iv[2] = l4.z; iv[3] = l4.w;
  }

  const int sq = qb0 + q0 + lk * 4;            // true q of acc rows (aligned 4)
  const int sp = (sq & ~31) + ((sq & 12) << 1) + ((sq & 16) >> 2);  // permuted base
#pragma unroll
  for (int dt = 0; dt < 4; ++dt) {
    const int d = dt * 16 + lr;                // C/D col
    if (PASS1) {
      uint2 o_;
      o_.x = (u32)f2b(acc[dt][0] * iv[0]) | ((u32)f2b(acc[dt][1] * iv[1]) << 16);
      o_.y = (u32)f2b(acc[dt][2] * iv[2]) | ((u32)f2b(acc[dt][3] * iv[3]) << 16);
      *(uint2*)(outp + (long)z * 65536 + (long)d * 1024 + sp) = o_;
    } else {
      uint2 ut = *(const uint2*)(bp + (long)z * 65536 + (long)d * 1024 + sp);
      float u0 = b2f(ut.x & 0xffffu), u1 = b2f(ut.x >> 16);
      float u2 = b2f(ut.y & 0xffffu), u3 = b2f(ut.y >> 16);
      long ob = (long)sq * 2048 + z * 64 + d;
      outp[ob]        = f2b(2.f * u0 - acc[dt][0] * iv[0]);
      outp[ob + 2048] = f2b(2.f * u1 - acc[dt][1] * iv[1]);
      outp[ob + 4096] = f2b(2.f * u2 - acc[dt][2] * iv[2]);
      outp[ob + 6144] = f2b(2.f * u3 - acc[dt][3] * iv[3]);
    }
  }
}

// ---------------- residual + LayerNorm (attn in bf16) ----------------
__global__ __launch_bounds__(256) void resid_ln(const float* __restrict__ h,
                                                const u16* __restrict__ attnb,
                                                const float* __restrict__ gamma,
                                                const float* __restrict__ beta,
                                                float* __restrict__ out) {
  __shared__ float rs[4], rs2[4];
  const long row = blockIdx.x;
  const int t = threadIdx.x;
  long base = (row << 10) + t * 4;
  float4 hv = *(const float4*)(h + base);
  uint2 av = *(const uint2*)(attnb + base);
  float a0 = b2f(av.x & 0xffffu), a1 = b2f(av.x >> 16);
  float a2 = b2f(av.y & 0xffffu), a3 = b2f(av.y >> 16);
  float x0 = hv.x + a0, x1 = hv.y + a1, x2 = hv.z + a2, x3 = hv.w + a3;
  float s = x0 + x1 + x2 + x3;
  float s2 = x0 * x0 + x1 * x1 + x2 * x2 + x3 * x3;
  for (int o = 32; o; o >>= 1) { s += __shfl_xor(s, o); s2 += __shfl_xor(s2, o); }
  int wid = t >> 6;
  if ((t & 63) == 0) { rs[wid] = s; rs2[wid] = s2; }
  __syncthreads();
  s = rs[0] + rs[1] + rs[2] + rs[3];
  s2 = rs2[0] + rs2[1] + rs2[2] + rs2[3];
  float mean = s * (1.f / 1024.f);
  float var = s2 * (1.f / 1024.f) - mean * mean;
  float rstd = rsqrtf(var + kEps);
  int d = t * 4;
  float4 g = *(const float4*)(gamma + d);
  float4 bt = *(const float4*)(beta + d);
  float4 o_;
  o_.x = (x0 - mean) * rstd * g.x + bt.x;
  o_.y = (x1 - mean) * rstd * g.y + bt.y;
  o_.z = (x2 - mean) * rstd * g.z + bt.z;
  o_.w = (x3 - mean) * rstd * g.w + bt.w;
  *(float4*)(out + base) = o_;
}

extern "C" void kernel_launch(void* const* d_in, const int* in_sizes, int n_in,
                              void* d_out, int out_size, void* d_ws, size_t ws_size,
                              hipStream_t stream) {
  const float* h = (const float*)d_in[0];
  const float* Wq = (const float*)d_in[1];
  const float* Wkv = (const float*)d_in[2];
  const float* Wo = (const float*)d_in[3];
  const float* gamma = (const float*)d_in[4];
  const float* beta = (const float*)d_in[5];
  float* out = (float*)d_out;

  char* ws = (char*)d_ws;
  size_t off = 0;
  auto alloc = [&](size_t bytes) -> void* {
    void* p = ws + off;
    off = (off + bytes + 255) & ~(size_t)255;
    return p;
  };
  u16* hb = (u16*)alloc(2097152ULL * 2);
  u16* Wqb = (u16*)alloc(1048576ULL * 2);     // contiguous with Wkvb -> one 3072-row panel
  u16* Wkvb = (u16*)alloc(2097152ULL * 2);
  u16* Wob = (u16*)alloc(1048576ULL * 2);
  u16* qb = (u16*)alloc(2097152ULL * 2);      // [S, B*N*DH]
  u16* kb = (u16*)alloc(2097152ULL * 2);      // [S, B*N*DH]
  u16* vtb = (u16*)alloc(2097152ULL * 2);     // [B,N,DH,S-perm]
  u16* Ut = (u16*)alloc(2097152ULL * 2);      // [B,N,DH,S-perm] (normalized U^T)
  float* linv = (float*)alloc(32768ULL * 4);  // [B,N,S]
  u16* vecb = (u16*)alloc(2097152ULL * 2);    // [S, B*N*DH]
  u16* attnb = (u16*)alloc(2097152ULL * 2);   // [S,B,D] bf16
  (void)ws_size; (void)n_in; (void)in_sizes; (void)out_size;
  (void)Wkvb;

  // fused casts (h, Wq, Wkv, Wo)
  cvt_all<<<6144, 256, 0, stream>>>(h, Wq, Wkv, Wo, hb, Wqb, Wkvb, Wob);

  // fused qkv: [q | k | v^T-perm] = h @ [Wq;Wkv]^T  (M=2048, N=3072, K=1024)
  // 128x96 tile (24 MFMA/wave/K-step), 512 blocks = exactly 2/CU, no tail.
  {
    GemmParams p{};
    p.A = hb; p.ldA = 1024;
    p.B = Wqb; p.ldB = 1024;                  // rows 0..3071: Wq then Wkv (contiguous)
    p.K = 1024; p.ob = qb; p.ob2 = kb; p.aux_b16 = vtb;
    gemm_tile<6, 128, 96, 4, 3><<<dim3(32, 16, 1), 256, 0, stream>>>(p);
  }
  // flash pass 1: U = softmax(qk/8) @ V -> Ut (normalized, permuted) + linv
  flash_tw<true><<<dim3(16, 32), 256, 0, stream>>>(qb, kb, vtb, linv, Ut);
  // flash pass 2: vec = 2U - (P @ U) * linv -> vecb
  flash_tw<false><<<dim3(16, 32), 256, 0, stream>>>(qb, kb, Ut, linv, vecb);
  // attn = vec @ Wo^T  (M=2048, N=1024, K=1024), bf16 out; 64x64 tile (512 blocks)
  {
    GemmParams p{};
    p.A = vecb; p.ldA = 1024;
    p.B = Wob; p.ldB = 1024;
    p.K = 1024; p.ob = attnb; p.ldO = 1024;
    gemm_tile<5, 64, 64, 2, 2><<<dim3(16, 32, 1), 256, 0, stream>>>(p);
  }
  // out = LN(h + attn) * gamma + beta
  resid_ln<<<2048, 256, 0, stream>>>(h, attnb, gamma, beta, out);
}